// Round 2
// baseline (878.458 us; speedup 1.0000x reference)
//
#include <hip/hip_runtime.h>
#include <hip/hip_bf16.h>

#define B_ 4
#define T_ 2048
#define D_ 256
#define H_ 4
#define DH_ 64

typedef __attribute__((ext_vector_type(8))) short short8;
typedef __attribute__((ext_vector_type(4))) float f32x4;
typedef unsigned short u16;
typedef unsigned char u8;

__device__ __forceinline__ float bf2f(u16 u) {
  union { unsigned int i; float f; } x; x.i = ((unsigned int)u) << 16; return x.f;
}
// round-to-nearest-even f32 -> bf16 (no NaN guard; data is finite)
__device__ __forceinline__ u16 f2bf(float f) {
  union { float f; unsigned int i; } x; x.f = f;
  unsigned int i = x.i;
  i += 0x7fffu + ((i >> 16) & 1u);
  return (u16)(i >> 16);
}

// ---------------------------------------------------------------------------
// wprep: transpose+convert the 5 weight matrices W[k][n] -> wt[m][n][k] bf16
// ---------------------------------------------------------------------------
__global__ __launch_bounds__(256) void wprep(
    const float* __restrict__ Wq, const float* __restrict__ Wk,
    const float* __restrict__ Wv, const float* __restrict__ Wpos,
    const float* __restrict__ Wout, u16* __restrict__ wt)
{
  __shared__ float tile[64][65];
  const float* Ws[5] = { Wq, Wk, Wv, Wpos, Wout };
  const int m = blockIdx.z;
  const float* W = Ws[m];
  const int tx = blockIdx.x * 64, ty = blockIdx.y * 64;
  const int c = threadIdx.x & 63, r0 = threadIdx.x >> 6;
#pragma unroll
  for (int it = 0; it < 16; ++it) {
    int r = r0 + it * 4;
    tile[r][c] = W[(size_t)(ty + r) * 256 + tx + c];
  }
  __syncthreads();
  u16* wo = wt + ((size_t)m << 16);
#pragma unroll
  for (int it = 0; it < 16; ++it) {
    int r = r0 + it * 4;
    wo[(size_t)(tx + r) * 256 + ty + c] = f2bf(tile[c][r]);
  }
}

// ---------------------------------------------------------------------------
// kproj: fused projections.
//   m=0: q=query@Wq+bq -> qu=q+u_bias, qv=q+v_bias  [b][h][t][dh] bf16
//   m=1: k=key@Wk                                    [b][h][t][dh] bf16
//   m=2: v=value@Wv stored TRANSPOSED               [b][h][dh][t] bf16
//   m=3: p=enc@Wpos                                  [h][t][dh]   bf16
// 4 waves/block, wave = 16 rows x 256 cols, K=256, mfma 16x16x32 bf16.
// ---------------------------------------------------------------------------
__global__ __launch_bounds__(256) void kproj(
    const float* __restrict__ query, const float* __restrict__ key_,
    const float* __restrict__ value, const float* __restrict__ enc,
    const float* __restrict__ bq, const float* __restrict__ ub,
    const float* __restrict__ vbias, const u16* __restrict__ wt,
    u16* __restrict__ qu, u16* __restrict__ qv, u16* __restrict__ kb,
    u16* __restrict__ vT, u16* __restrict__ pb)
{
  const int m = blockIdx.y;
  if (m == 3 && blockIdx.x >= T_ / 64) return;
  const int w = threadIdx.x >> 6, lane = threadIdx.x & 63;
  const int g = lane >> 4, c = lane & 15;
  const int rowblk = blockIdx.x * 64 + w * 16;
  const float* src = (m == 0) ? query : (m == 1) ? key_ : (m == 2) ? value : enc;

  // A fragments: row = rowblk + c (lane&15), k = kc*32 + g*8 + e (contiguous 8)
  const float* ap = src + (size_t)(rowblk + c) * D_;
  short8 afr[8];
#pragma unroll
  for (int kc = 0; kc < 8; ++kc) {
    const float* p = ap + kc * 32 + g * 8;
    float4 x0 = *reinterpret_cast<const float4*>(p);
    float4 x1 = *reinterpret_cast<const float4*>(p + 4);
    short8 s;
    s[0]=(short)f2bf(x0.x); s[1]=(short)f2bf(x0.y); s[2]=(short)f2bf(x0.z); s[3]=(short)f2bf(x0.w);
    s[4]=(short)f2bf(x1.x); s[5]=(short)f2bf(x1.y); s[6]=(short)f2bf(x1.z); s[7]=(short)f2bf(x1.w);
    afr[kc] = s;
  }
  const u16* wtm = wt + ((size_t)m << 16);
  f32x4 acc[16];
#pragma unroll
  for (int nt = 0; nt < 16; ++nt) acc[nt] = (f32x4){0.f,0.f,0.f,0.f};
#pragma unroll
  for (int nt = 0; nt < 16; ++nt) {
    const u16* wrow = wtm + (size_t)(nt * 16 + c) * D_;
#pragma unroll
    for (int kc = 0; kc < 8; ++kc) {
      short8 bfr = *reinterpret_cast<const short8*>(wrow + kc * 32 + g * 8);
      acc[nt] = __builtin_amdgcn_mfma_f32_16x16x32_bf16(afr[kc], bfr, acc[nt], 0, 0, 0);
    }
  }
  // C frag: row = g*4+r, col n = nt*16+c
  int Rr[4], br[4], tr[4];
#pragma unroll
  for (int r = 0; r < 4; ++r) {
    Rr[r] = rowblk + g * 4 + r; br[r] = Rr[r] >> 11; tr[r] = Rr[r] & (T_ - 1);
  }
  if (m == 0) {
#pragma unroll
    for (int nt = 0; nt < 16; ++nt) {
      int n = nt * 16 + c; int h = n >> 6; int dh = n & 63;
      float bqv = bq[n], uu = ub[n], vv = vbias[n];
#pragma unroll
      for (int r = 0; r < 4; ++r) {
        size_t o = ((size_t)(br[r] * H_ + h) * T_ + tr[r]) * DH_ + dh;
        float q = acc[nt][r] + bqv;
        qu[o] = f2bf(q + uu);
        qv[o] = f2bf(q + vv);
      }
    }
  } else if (m == 1) {
#pragma unroll
    for (int nt = 0; nt < 16; ++nt) {
      int n = nt * 16 + c; int h = n >> 6; int dh = n & 63;
#pragma unroll
      for (int r = 0; r < 4; ++r) {
        size_t o = ((size_t)(br[r] * H_ + h) * T_ + tr[r]) * DH_ + dh;
        kb[o] = f2bf(acc[nt][r]);
      }
    }
  } else if (m == 2) {
#pragma unroll
    for (int nt = 0; nt < 16; ++nt) {
      int n = nt * 16 + c; int h = n >> 6; int dh = n & 63;
#pragma unroll
      for (int r = 0; r < 4; ++r)
        vT[((size_t)(br[r] * H_ + h) * DH_ + dh) * T_ + tr[r]] = f2bf(acc[nt][r]);
    }
  } else {
#pragma unroll
    for (int nt = 0; nt < 16; ++nt) {
      int n = nt * 16 + c; int h = n >> 6; int dh = n & 63;
#pragma unroll
      for (int r = 0; r < 4; ++r)
        pb[((size_t)h * T_ + Rr[r]) * DH_ + dh] = f2bf(acc[nt][r]);
    }
  }
}

// ---------------------------------------------------------------------------
// kposshift: E[t1,s] = qv[t1] . p[s], stored PRE-SHIFTED as bf16 at flat
// f = t1*(T+1)+s+1-T (f>=0). Position j=i+1 is never written (read gives 0).
// SS = log2(byte stride): 1 = dense ushort buffer, 2 = packed into f32 slots.
// ---------------------------------------------------------------------------
template<int SS>
__global__ __launch_bounds__(256) void kposshift(
    const u16* __restrict__ qv, const u16* __restrict__ pb, char* shiftbase)
{
  const int w = threadIdx.x >> 6, lane = threadIdx.x & 63;
  const int g = lane >> 4, c = lane & 15;
  const int b = blockIdx.z, h = blockIdx.y;
  const int i0 = blockIdx.x * 64 + w * 16;
  const size_t bh = (size_t)b * H_ + h;
  const u16* qrow = qv + (bh * T_ + i0 + c) * DH_;
  short8 a0 = *reinterpret_cast<const short8*>(qrow + g * 8);
  short8 a1 = *reinterpret_cast<const short8*>(qrow + 32 + g * 8);
  char* sh = shiftbase + ((bh * (size_t)T_ * T_) << SS);
  const u16* pbase = pb + (size_t)h * T_ * DH_;
  for (int s0 = 0; s0 < T_; s0 += 16) {
    const u16* prow = pbase + (size_t)(s0 + c) * DH_;
    short8 b0 = *reinterpret_cast<const short8*>(prow + g * 8);
    short8 b1 = *reinterpret_cast<const short8*>(prow + 32 + g * 8);
    f32x4 acc = (f32x4){0.f,0.f,0.f,0.f};
    acc = __builtin_amdgcn_mfma_f32_16x16x32_bf16(a0, b0, acc, 0, 0, 0);
    acc = __builtin_amdgcn_mfma_f32_16x16x32_bf16(a1, b1, acc, 0, 0, 0);
#pragma unroll
    for (int r = 0; r < 4; ++r) {
      int t1 = i0 + g * 4 + r;
      int f = t1 * (T_ + 1) + (s0 + c) + 1 - T_;
      if (f >= 0) *reinterpret_cast<u16*>(sh + ((size_t)f << SS)) = f2bf(acc[r]);
    }
  }
}

// ---------------------------------------------------------------------------
// kattn: per (b,h,64-row block). Sweep1: scores -> lazy online max/l.
// Sweep2: recompute scores, write normalized attn (f32), PV via LDS-staged
// bf16 attn tile + transposed V.  NOTE: attn & shiftbase may alias (packed
// fallback) -> no __restrict__ on them.
// ---------------------------------------------------------------------------
template<int SS>
__device__ __forceinline__ void score16(
    const u16* __restrict__ kbase, const char* shb, const u8* __restrict__ mrow,
    short8 a0, short8 a1, int j0, int g, int c, const int* irow, float* s)
{
  const u16* krow = kbase + (size_t)(j0 + c) * DH_;
  short8 b0 = *reinterpret_cast<const short8*>(krow + g * 8);
  short8 b1 = *reinterpret_cast<const short8*>(krow + 32 + g * 8);
  f32x4 acc = (f32x4){0.f,0.f,0.f,0.f};
  acc = __builtin_amdgcn_mfma_f32_16x16x32_bf16(a0, b0, acc, 0, 0, 0);
  acc = __builtin_amdgcn_mfma_f32_16x16x32_bf16(a1, b1, acc, 0, 0, 0);
  const int j = j0 + c;
  const bool mk = mrow[j] != 0;
#pragma unroll
  for (int r = 0; r < 4; ++r) {
    float sv = (j == irow[r] + 1) ? 0.f
             : bf2f(*reinterpret_cast<const u16*>(shb + (((size_t)irow[r] * T_ + j) << SS)));
    s[r] = mk ? -1e9f : (acc[r] + sv) * 0.0625f;
  }
}

template<int SS>
__global__ __launch_bounds__(256) void kattn(
    const u16* __restrict__ qu, const u16* __restrict__ kb,
    const u16* __restrict__ vT, const char* shiftbase,
    const u8* __restrict__ mask, float* attn, float* __restrict__ ctx)
{
  __shared__ __align__(16) u16 plds[4][16][40];   // pad 40: 16B-aligned rows, ~2-way banks
  const int w = threadIdx.x >> 6, lane = threadIdx.x & 63;
  const int g = lane >> 4, c = lane & 15;
  const int b = blockIdx.z, h = blockIdx.y;
  const int i0 = blockIdx.x * 64 + w * 16;
  const size_t bh = (size_t)b * H_ + h;
  const u16* qrow = qu + (bh * T_ + i0 + c) * DH_;
  const short8 a0 = *reinterpret_cast<const short8*>(qrow + g * 8);
  const short8 a1 = *reinterpret_cast<const short8*>(qrow + 32 + g * 8);
  const u16* kbase = kb + bh * (size_t)T_ * DH_;
  const char* shb = shiftbase + ((bh * (size_t)T_ * T_) << SS);
  const u8* mrow = mask + b * T_;
  int irow[4];
#pragma unroll
  for (int r = 0; r < 4; ++r) irow[r] = i0 + g * 4 + r;

  // ---- sweep 1: lazy online softmax stats (ref point m, exact algebra) ----
  float mx[4], lx[4];
#pragma unroll
  for (int r = 0; r < 4; ++r) { mx[r] = 0.f; lx[r] = 0.f; }
  for (int j0 = 0; j0 < T_; j0 += 16) {
    float s[4];
    score16<SS>(kbase, shb, mrow, a0, a1, j0, g, c, irow, s);
#pragma unroll
    for (int r = 0; r < 4; ++r) {
      float d = s[r] - mx[r];
      if (__builtin_expect(d > 20.f, 0)) { lx[r] = lx[r] * __expf(-d) + 1.f; mx[r] = s[r]; }
      else lx[r] += __expf(d);
    }
  }
  // reduce (m,l) across the 16-lane column group
  float mf[4], invl[4];
#pragma unroll
  for (int r = 0; r < 4; ++r) {
    float mm = mx[r];
    mm = fmaxf(mm, __shfl_xor(mm, 1, 64));
    mm = fmaxf(mm, __shfl_xor(mm, 2, 64));
    mm = fmaxf(mm, __shfl_xor(mm, 4, 64));
    mm = fmaxf(mm, __shfl_xor(mm, 8, 64));
    float lf = lx[r] * __expf(mx[r] - mm);
    lf += __shfl_xor(lf, 1, 64);
    lf += __shfl_xor(lf, 2, 64);
    lf += __shfl_xor(lf, 4, 64);
    lf += __shfl_xor(lf, 8, 64);
    mf[r] = mm; invl[r] = 1.f / lf;
  }

  // ---- sweep 2: recompute scores, write attn, PV accumulate ----
  f32x4 cacc[4];
#pragma unroll
  for (int nt = 0; nt < 4; ++nt) cacc[nt] = (f32x4){0.f,0.f,0.f,0.f};
  float* abase = attn + bh * (size_t)T_ * T_;
  const u16* vbase = vT + bh * (size_t)DH_ * T_;

  for (int jt = 0; jt < T_; jt += 32) {
#pragma unroll
    for (int half = 0; half < 2; ++half) {
      const int j0 = jt + half * 16;
      float s[4];
      score16<SS>(kbase, shb, mrow, a0, a1, j0, g, c, irow, s);
#pragma unroll
      for (int r = 0; r < 4; ++r) {
        float at = __expf(s[r] - mf[r]) * invl[r];
        abase[(size_t)irow[r] * T_ + (j0 + c)] = at;
        plds[w][g * 4 + r][half * 16 + c] = f2bf(at);
      }
    }
    // A frag of attn tile: row = c, k = g*8+e  (wave-local LDS, no barrier)
    short8 pa = *reinterpret_cast<const short8*>(&plds[w][c][g * 8]);
#pragma unroll
    for (int nt = 0; nt < 4; ++nt) {
      short8 vb8 = *reinterpret_cast<const short8*>(vbase + (size_t)(nt * 16 + c) * T_ + jt + g * 8);
      cacc[nt] = __builtin_amdgcn_mfma_f32_16x16x32_bf16(pa, vb8, cacc[nt], 0, 0, 0);
    }
  }
#pragma unroll
  for (int nt = 0; nt < 4; ++nt) {
    int dh = nt * 16 + c;
#pragma unroll
    for (int r = 0; r < 4; ++r)
      ctx[((size_t)b * T_ + irow[r]) * D_ + h * DH_ + dh] = cacc[nt][r];
  }
}

// ---------------------------------------------------------------------------
// kout: out = ctx @ Wout + bout   (ctx f32 -> bf16 on the fly)
// ---------------------------------------------------------------------------
__global__ __launch_bounds__(256) void kout(
    const float* __restrict__ ctx, const u16* __restrict__ wtout,
    const float* __restrict__ bout, float* __restrict__ out)
{
  const int w = threadIdx.x >> 6, lane = threadIdx.x & 63;
  const int g = lane >> 4, c = lane & 15;
  const int rowblk = blockIdx.x * 64 + w * 16;
  const float* ap = ctx + (size_t)(rowblk + c) * D_;
  short8 afr[8];
#pragma unroll
  for (int kc = 0; kc < 8; ++kc) {
    const float* p = ap + kc * 32 + g * 8;
    float4 x0 = *reinterpret_cast<const float4*>(p);
    float4 x1 = *reinterpret_cast<const float4*>(p + 4);
    short8 s;
    s[0]=(short)f2bf(x0.x); s[1]=(short)f2bf(x0.y); s[2]=(short)f2bf(x0.z); s[3]=(short)f2bf(x0.w);
    s[4]=(short)f2bf(x1.x); s[5]=(short)f2bf(x1.y); s[6]=(short)f2bf(x1.z); s[7]=(short)f2bf(x1.w);
    afr[kc] = s;
  }
  f32x4 acc[16];
#pragma unroll
  for (int nt = 0; nt < 16; ++nt) acc[nt] = (f32x4){0.f,0.f,0.f,0.f};
#pragma unroll
  for (int nt = 0; nt < 16; ++nt) {
    const u16* wrow = wtout + (size_t)(nt * 16 + c) * D_;
#pragma unroll
    for (int kc = 0; kc < 8; ++kc) {
      short8 bfr = *reinterpret_cast<const short8*>(wrow + kc * 32 + g * 8);
      acc[nt] = __builtin_amdgcn_mfma_f32_16x16x32_bf16(afr[kc], bfr, acc[nt], 0, 0, 0);
    }
  }
#pragma unroll
  for (int nt = 0; nt < 16; ++nt) {
    int n = nt * 16 + c;
    float bo = bout[n];
#pragma unroll
    for (int r = 0; r < 4; ++r)
      out[(size_t)(rowblk + g * 4 + r) * D_ + n] = acc[nt][r] + bo;
  }
}

// ---------------------------------------------------------------------------
extern "C" void kernel_launch(void* const* d_in, const int* in_sizes, int n_in,
                              void* d_out, int out_size, void* d_ws, size_t ws_size,
                              hipStream_t stream)
{
  (void)in_sizes; (void)n_in; (void)out_size;
  const float* query = (const float*)d_in[0];
  const float* key_  = (const float*)d_in[1];
  const float* value = (const float*)d_in[2];
  const u8*    mask  = (const u8*)d_in[3];
  const float* enc   = (const float*)d_in[4];
  const float* Wq    = (const float*)d_in[5];
  const float* bq    = (const float*)d_in[6];
  const float* Wk    = (const float*)d_in[7];
  const float* Wv    = (const float*)d_in[8];
  const float* Wpos  = (const float*)d_in[9];
  const float* ub    = (const float*)d_in[10];
  const float* vb    = (const float*)d_in[11];
  const float* Wout  = (const float*)d_in[12];
  const float* bout  = (const float*)d_in[13];

  float* out  = (float*)d_out;
  float* attn = out + (size_t)B_ * T_ * D_;

  size_t off = 0;
  char* ws = (char*)d_ws;
  auto alloc = [&](size_t bytes) -> char* {
    char* p = ws + off; off += (bytes + 255) & ~(size_t)255; return p;
  };
  u16* qu = (u16*)alloc((size_t)B_ * H_ * T_ * DH_ * 2);
  u16* qv = (u16*)alloc((size_t)B_ * H_ * T_ * DH_ * 2);
  u16* kb = (u16*)alloc((size_t)B_ * H_ * T_ * DH_ * 2);
  u16* vT = (u16*)alloc((size_t)B_ * H_ * T_ * DH_ * 2);
  u16* pb = (u16*)alloc((size_t)H_ * T_ * DH_ * 2);
  u16* wt = (u16*)alloc((size_t)5 * 256 * 256 * 2);
  float* ctx = (float*)alloc((size_t)B_ * T_ * D_ * 4);
  const size_t shift_bytes = (size_t)B_ * H_ * T_ * T_ * 2;
  bool packed; char* shiftb;
  if (ws_size >= off + shift_bytes) { shiftb = alloc(shift_bytes); packed = false; }
  else { shiftb = (char*)attn; packed = true; }  // pack bf16 into f32 slots of attn

  dim3 blk(256);
  wprep<<<dim3(4, 4, 5), blk, 0, stream>>>(Wq, Wk, Wv, Wpos, Wout, wt);
  kproj<<<dim3(128, 4), blk, 0, stream>>>(query, key_, value, enc, bq, ub, vb, wt,
                                          qu, qv, kb, vT, pb);
  if (!packed) {
    kposshift<1><<<dim3(32, 4, 4), blk, 0, stream>>>(qv, pb, shiftb);
    kattn<1><<<dim3(32, 4, 4), blk, 0, stream>>>(qu, kb, vT, shiftb, mask, attn, ctx);
  } else {
    kposshift<2><<<dim3(32, 4, 4), blk, 0, stream>>>(qv, pb, shiftb);
    kattn<2><<<dim3(32, 4, 4), blk, 0, stream>>>(qu, kb, vT, shiftb, mask, attn, ctx);
  }
  kout<<<dim3(128), blk, 0, stream>>>(ctx, wt + 4 * 65536, bout, out);
}